// Round 5
// baseline (1020.369 us; speedup 1.0000x reference)
//
#include <hip/hip_runtime.h>

#define TOKENS 8192
#define DIM 1024
#define NEXP 8
#define FDIM 4096

typedef __bf16 bf16x8 __attribute__((ext_vector_type(8)));
typedef float f32x4 __attribute__((ext_vector_type(4)));

__device__ __forceinline__ unsigned short f2bf(float f) {
  unsigned u = __builtin_bit_cast(unsigned, f);
  u += 0x7fffu + ((u >> 16) & 1u);
  return (unsigned short)(u >> 16);
}

__device__ __forceinline__ float bf2f(unsigned short s) {
  unsigned u = (unsigned)s << 16;
  return __builtin_bit_cast(float, u);
}

__device__ __forceinline__ void gload16(const void* g, void* l) {
  __builtin_amdgcn_global_load_lds(
      (const __attribute__((address_space(1))) unsigned int*)g,
      (__attribute__((address_space(3))) unsigned int*)l, 16, 0, 0);
}

// ---------------- router ----------------
__global__ void zero_counts_kernel(int* counts) {
  if (threadIdx.x < NEXP) counts[threadIdx.x] = 0;
}

__global__ void scan_kernel(const int* counts, int* offs) {
  if (threadIdx.x == 0) {
    int s = 0;
    for (int e = 0; e < NEXP; ++e) { offs[e] = s; s += counts[e]; }
    offs[NEXP] = s;
  }
}

__global__ void router_kernel(const float* __restrict__ hs,
                              const float* __restrict__ gw,
                              const float* __restrict__ gb,
                              int* __restrict__ counts,
                              int* __restrict__ tok_idx,
                              float* __restrict__ tok_w,
                              unsigned int* __restrict__ slotinfo,
                              unsigned short* __restrict__ hs_bf) {
  const int lane = threadIdx.x & 63;
  const int wid = threadIdx.x >> 6;
  const int t = blockIdx.x * 4 + wid;
  const float* row = hs + (size_t)t * DIM;

  float x[16];
  const float4* r4 = (const float4*)(row + lane * 16);
#pragma unroll
  for (int i = 0; i < 4; ++i) {
    float4 v = r4[i];
    x[i * 4 + 0] = v.x; x[i * 4 + 1] = v.y; x[i * 4 + 2] = v.z; x[i * 4 + 3] = v.w;
  }

  float acc[8];
#pragma unroll
  for (int e = 0; e < 8; ++e) acc[e] = 0.f;
#pragma unroll
  for (int i = 0; i < 16; ++i) {
    const int d = lane * 16 + i;
    const float4* g4 = (const float4*)(gw + (size_t)d * 8);
    float4 g0 = g4[0], g1 = g4[1];
    const float xv = x[i];
    acc[0] += xv * g0.x; acc[1] += xv * g0.y; acc[2] += xv * g0.z; acc[3] += xv * g0.w;
    acc[4] += xv * g1.x; acc[5] += xv * g1.y; acc[6] += xv * g1.z; acc[7] += xv * g1.w;
  }
#pragma unroll
  for (int sh = 1; sh < 64; sh <<= 1) {
#pragma unroll
    for (int e = 0; e < 8; ++e) acc[e] += __shfl_xor(acc[e], sh, 64);
  }
#pragma unroll
  for (int e = 0; e < 8; ++e) acc[e] += gb[e];

  float mx = acc[0];
#pragma unroll
  for (int e = 1; e < 8; ++e) mx = fmaxf(mx, acc[e]);
  float p[8];
  float sum = 0.f;
#pragma unroll
  for (int e = 0; e < 8; ++e) { p[e] = __expf(acc[e] - mx); sum += p[e]; }
  const float inv = 1.0f / sum;

  int i0 = 0; float b0 = p[0];
#pragma unroll
  for (int e = 1; e < 8; ++e) if (p[e] > b0) { b0 = p[e]; i0 = e; }
  int i1 = -1; float b1v = -1.f;
#pragma unroll
  for (int e = 0; e < 8; ++e) if (e != i0 && p[e] > b1v) { b1v = p[e]; i1 = e; }

  if (lane == 0) {
    int pos0 = atomicAdd(&counts[i0], 1);
    tok_idx[i0 * TOKENS + pos0] = t;
    tok_w[i0 * TOKENS + pos0] = b0 * inv;
    slotinfo[t * 2 + 0] = ((unsigned)i0 << 13) | (unsigned)pos0;
    int pos1 = atomicAdd(&counts[i1], 1);
    tok_idx[i1 * TOKENS + pos1] = t;
    tok_w[i1 * TOKENS + pos1] = b1v * inv;
    slotinfo[t * 2 + 1] = ((unsigned)i1 << 13) | (unsigned)pos1;
  }

  unsigned short us[16];
#pragma unroll
  for (int i = 0; i < 16; ++i) us[i] = f2bf(x[i]);
  uint4 o0, o1;
  o0.x = (unsigned)us[0] | ((unsigned)us[1] << 16);
  o0.y = (unsigned)us[2] | ((unsigned)us[3] << 16);
  o0.z = (unsigned)us[4] | ((unsigned)us[5] << 16);
  o0.w = (unsigned)us[6] | ((unsigned)us[7] << 16);
  o1.x = (unsigned)us[8] | ((unsigned)us[9] << 16);
  o1.y = (unsigned)us[10] | ((unsigned)us[11] << 16);
  o1.z = (unsigned)us[12] | ((unsigned)us[13] << 16);
  o1.w = (unsigned)us[14] | ((unsigned)us[15] << 16);
  uint4* dst = (uint4*)(hs_bf + (size_t)t * DIM + lane * 16);
  dst[0] = o0;
  dst[1] = o1;
}

// ---------------- transpose + cast weights: src[e][R][C] f32 -> dst[e][C][R] bf16 ----------------
__global__ void cast_transpose_kernel(const float* __restrict__ src,
                                      unsigned short* __restrict__ dst,
                                      int R, int C) {
  __shared__ float tile[64][65];
  const int e = blockIdx.z;
  const int r0 = blockIdx.y * 64;
  const int c0 = blockIdx.x * 64;
  const float* s = src + (size_t)e * R * C;
  unsigned int* d = (unsigned int*)(dst + (size_t)e * R * C);

#pragma unroll
  for (int i = 0; i < 16; ++i) {
    const int idx = threadIdx.x + i * 256;
    const int r = idx >> 6;
    const int c = idx & 63;
    tile[r][c] = s[(size_t)(r0 + r) * C + (c0 + c)];
  }
  __syncthreads();
#pragma unroll
  for (int i = 0; i < 8; ++i) {
    const int idx = threadIdx.x + i * 256;
    const int c = idx >> 5;
    const int r = (idx & 31) * 2;
    unsigned pk = (unsigned)f2bf(tile[r][c]) | ((unsigned)f2bf(tile[r + 1][c]) << 16);
    d[((size_t)(c0 + c) * R + (r0 + r)) >> 1] = pk;
  }
}

// ---------------- grouped GEMM: 256x256, BK=32, A in 4-slot LDS ring, B direct-to-register ----
// MODE 0: h_buf[goff+pos] = gelu(gather(hs_bf) @ w1t^T + b1)   (K=1024, N=4096)
// MODE 1: y_buf[goff+pos] =        h_buf       @ w2t^T + b2    (K=4096, N=1024)
//
// Per tile t: issue stage-A(t+3) (2 gload_lds) + load B(t+1) (4 dwordx4 -> regs),
// MFMA C0 (a0cur x Bcur), gate {vmcnt lgkm(0)} + s_barrier, ds_read a0next(t+1),
// MFMA C1 (a1r x Bcur).  Gate suffix math (6 issues/tile = A2+B4, in-order retire):
// steady vmcnt(12) leaves tiles t-1,t outstanding => A(t+1) (issued t-2) landed.
// Tile 0 needs vmcnt(8) (prologue queue shape). Tail: 12,12,12,none.

#define MOE_TILE(SB, SNB, WB, BCUR, BNXT, A0C, A0N, DOA, DOB, GATE, DOGATE, READN)  \
  {                                                                                 \
    bf16x8 a1r_[4];                                                                 \
    _Pragma("unroll") for (int f_ = 0; f_ < 4; ++f_)                                \
      a1r_[f_] = *(const bf16x8*)((SB) + aoff[4 + f_]);                             \
    if (DOA) {                                                                      \
      gload16(aS0, (WB));                                                           \
      gload16(aS1, (WB) + 8192);                                                    \
      aS0 += 64; aS1 += 64;                                                         \
    }                                                                               \
    if (DOB) {                                                                      \
      _Pragma("unroll") for (int g_ = 0; g_ < 4; ++g_) {                            \
        BNXT[g_] = *(const bf16x8*)bP[g_];                                          \
        bP[g_] += 64;                                                               \
      }                                                                             \
    }                                                                               \
    __builtin_amdgcn_sched_barrier(0);                                              \
    __builtin_amdgcn_s_setprio(1);                                                  \
    _Pragma("unroll") for (int f_ = 0; f_ < 4; ++f_)                                \
      _Pragma("unroll") for (int g_ = 0; g_ < 4; ++g_)                              \
        acc[f_][g_] = __builtin_amdgcn_mfma_f32_16x16x32_bf16(                      \
            A0C[f_], BCUR[g_], acc[f_][g_], 0, 0, 0);                               \
    __builtin_amdgcn_s_setprio(0);                                                  \
    __builtin_amdgcn_sched_barrier(0);                                              \
    if (DOGATE) {                                                                   \
      asm volatile(GATE ::: "memory");                                              \
      __builtin_amdgcn_sched_barrier(0);                                            \
      __builtin_amdgcn_s_barrier();                                                 \
      __builtin_amdgcn_sched_barrier(0);                                            \
    }                                                                               \
    if (READN) {                                                                    \
      _Pragma("unroll") for (int f_ = 0; f_ < 4; ++f_)                              \
        A0N[f_] = *(const bf16x8*)((SNB) + aoff[f_]);                               \
    }                                                                               \
    __builtin_amdgcn_sched_barrier(0);                                              \
    __builtin_amdgcn_s_setprio(1);                                                  \
    _Pragma("unroll") for (int f_ = 0; f_ < 4; ++f_)                                \
      _Pragma("unroll") for (int g_ = 0; g_ < 4; ++g_)                              \
        acc[4 + f_][g_] = __builtin_amdgcn_mfma_f32_16x16x32_bf16(                  \
            a1r_[f_], BCUR[g_], acc[4 + f_][g_], 0, 0, 0);                          \
    __builtin_amdgcn_s_setprio(0);                                                  \
    __builtin_amdgcn_sched_barrier(0);                                              \
  }

template<int MODE, int K, int N>
__global__ __launch_bounds__(512, 2)
void moe_gemm(const unsigned short* __restrict__ Abase,
              const unsigned short* __restrict__ Bbase,
              const float* __restrict__ bias,
              const int* __restrict__ counts,
              const int* __restrict__ offs,
              const int* __restrict__ tok_idx,
              unsigned short* __restrict__ dst) {
  constexpr int NT = K / 32;  // K-tiles (multiple of 4, >= 8)
  __shared__ __align__(16) unsigned char sm[65536];  // A ring: 4 slots x 16 KB

  const int e = blockIdx.z;
  const int cnt = counts[e];
  const int m0 = blockIdx.y * 256;
  if (m0 >= cnt) return;
  const int n0 = blockIdx.x * 256;
  const int goff = offs[e];

  const int tid = threadIdx.x;
  const int lane = tid & 63;
  const int wid = tid >> 6;
  const int wr = wid >> 2;   // 0..1 : M band (128 rows)
  const int wcn = wid & 3;   // 0..3 : N band (64 cols)
  const int l15 = lane & 15;
  const int cg = lane >> 4;  // 0..3 : 16B chunk group within 64B row
  const int wdst = wid * 1024;

  // ---- A staging source addresses (per thread: rows urow and urow+128) ----
  const int urow = tid >> 2;
  const int uchk = tid & 3;
  const int swz = uchk ^ ((urow >> 1) & 3);  // source pre-swizzle (read-side matched)

  int gA0 = m0 + urow;       if (gA0 > cnt - 1) gA0 = cnt - 1;
  int gA1 = m0 + urow + 128; if (gA1 > cnt - 1) gA1 = cnt - 1;
  size_t rowA0, rowA1;
  if (MODE == 0) {
    rowA0 = (size_t)tok_idx[e * TOKENS + gA0] * K;
    rowA1 = (size_t)tok_idx[e * TOKENS + gA1] * K;
  } else {
    rowA0 = (size_t)(goff + gA0) * K;
    rowA1 = (size_t)(goff + gA1) * K;
  }
  const unsigned char* aS0 = (const unsigned char*)(Abase + rowA0) + swz * 16;
  const unsigned char* aS1 = (const unsigned char*)(Abase + rowA1) + swz * 16;

  // ---- B direct-load pointers (one 16B frag per g, advance 64B per tile) ----
  const unsigned char* Bexp = (const unsigned char*)(Bbase + (size_t)e * K * N);
  const unsigned char* bP[4];
#pragma unroll
  for (int g = 0; g < 4; ++g)
    bP[g] = Bexp + (size_t)(n0 + wcn * 64 + g * 16 + l15) * (K * 2) + cg * 16;

  // ---- ds_read fragment byte offsets (loop-invariant) ----
  int aoff[8];
#pragma unroll
  for (int f = 0; f < 8; ++f) {
    const int r = wr * 128 + f * 16 + l15;
    aoff[f] = r * 64 + ((cg ^ ((r >> 1) & 3)) * 16);
  }

  f32x4 acc[8][4];
  const f32x4 fz = {0.f, 0.f, 0.f, 0.f};
#pragma unroll
  for (int f = 0; f < 8; ++f)
#pragma unroll
    for (int g = 0; g < 4; ++g) acc[f][g] = fz;

  bf16x8 BbA[4], BbB[4];
  bf16x8 a0X[4], a0Y[4];

  // ---- prologue: B(0) first, then stage A-tiles 0,1,2 ----
#pragma unroll
  for (int g = 0; g < 4; ++g) { BbA[g] = *(const bf16x8*)bP[g]; bP[g] += 64; }
#pragma unroll
  for (int j = 0; j < 3; ++j) {
    gload16(aS0, sm + j * 16384 + wdst);
    gload16(aS1, sm + j * 16384 + wdst + 8192);
    aS0 += 64; aS1 += 64;
  }
  asm volatile("s_waitcnt vmcnt(4)" ::: "memory");  // B(0) + A(0) landed
  __builtin_amdgcn_sched_barrier(0);
  __builtin_amdgcn_s_barrier();

  const unsigned char* smc = (const unsigned char*)sm;
#pragma unroll
  for (int f = 0; f < 4; ++f) a0X[f] = *(const bf16x8*)(smc + aoff[f]);

  // slot bases
  const unsigned char* S0 = smc;
  const unsigned char* S1 = smc + 16384;
  const unsigned char* S2 = smc + 32768;
  const unsigned char* S3 = smc + 49152;
  unsigned char* W0 = (unsigned char*)sm + wdst;
  unsigned char* W1 = (unsigned char*)sm + 16384 + wdst;
  unsigned char* W2 = (unsigned char*)sm + 32768 + wdst;
  unsigned char* W3 = (unsigned char*)sm + 49152 + wdst;

  // ---- tiles 0..3 peeled (tile 0 gate = vmcnt(8)) ----
  MOE_TILE(S0, S1, W3, BbA, BbB, a0X, a0Y, 1, 1, "s_waitcnt vmcnt(8) lgkmcnt(0)", 1, 1);
  MOE_TILE(S1, S2, W0, BbB, BbA, a0Y, a0X, 1, 1, "s_waitcnt vmcnt(12) lgkmcnt(0)", 1, 1);
  MOE_TILE(S2, S3, W1, BbA, BbB, a0X, a0Y, 1, 1, "s_waitcnt vmcnt(12) lgkmcnt(0)", 1, 1);
  MOE_TILE(S3, S0, W2, BbB, BbA, a0Y, a0X, 1, 1, "s_waitcnt vmcnt(12) lgkmcnt(0)", 1, 1);

  // ---- main loop: tiles 4 .. NT-5 (4 per iteration) ----
#pragma unroll 1
  for (int t = 4; t + 7 < NT; t += 4) {
    MOE_TILE(S0, S1, W3, BbA, BbB, a0X, a0Y, 1, 1, "s_waitcnt vmcnt(12) lgkmcnt(0)", 1, 1);
    MOE_TILE(S1, S2, W0, BbB, BbA, a0Y, a0X, 1, 1, "s_waitcnt vmcnt(12) lgkmcnt(0)", 1, 1);
    MOE_TILE(S2, S3, W1, BbA, BbB, a0X, a0Y, 1, 1, "s_waitcnt vmcnt(12) lgkmcnt(0)", 1, 1);
    MOE_TILE(S3, S0, W2, BbB, BbA, a0Y, a0X, 1, 1, "s_waitcnt vmcnt(12) lgkmcnt(0)", 1, 1);
  }

  // ---- tail: tiles NT-4 .. NT-1 ----
  MOE_TILE(S0, S1, W3, BbA, BbB, a0X, a0Y, 1, 1, "s_waitcnt vmcnt(12) lgkmcnt(0)", 1, 1);
  MOE_TILE(S1, S2, W0, BbB, BbA, a0Y, a0X, 0, 1, "s_waitcnt vmcnt(12) lgkmcnt(0)", 1, 1);
  MOE_TILE(S2, S3, W1, BbA, BbB, a0X, a0Y, 0, 1, "s_waitcnt vmcnt(12) lgkmcnt(0)", 1, 1);
  MOE_TILE(S3, S0, W2, BbB, BbA, a0Y, a0X, 0, 0, "", 0, 0);

  // ---- epilogue ----
#pragma unroll
  for (int g = 0; g < 4; ++g) {
    const int fcol = n0 + wcn * 64 + g * 16 + l15;
    const float bv = bias[e * N + fcol];
#pragma unroll
    for (int f = 0; f < 8; ++f) {
#pragma unroll
      for (int j = 0; j < 4; ++j) {
        const int ml = wr * 128 + f * 16 + cg * 4 + j;
        const int gm = m0 + ml;
        if (gm < cnt) {
          float v = acc[f][g][j] + bv;
          if (MODE == 0) {
            const float u = 0.7978845608028654f * (v + 0.044715f * v * v * v);
            const float th = 1.0f - 2.0f / (1.0f + __expf(2.0f * u));
            v = 0.5f * v * (1.0f + th);
          }
          dst[(size_t)(goff + gm) * N + fcol] = f2bf(v);
        }
      }
    }
  }
}

// ---------------- fused combine + residual + layernorm ----------------
__global__ void ln_combine_kernel(const unsigned short* __restrict__ y_buf,
                                  const float* __restrict__ in_t,
                                  const int* __restrict__ offs,
                                  const unsigned int* __restrict__ slotinfo,
                                  const float* __restrict__ tok_w,
                                  const float* __restrict__ gamma,
                                  const float* __restrict__ beta,
                                  float* __restrict__ out) {
  const int lane = threadIdx.x & 63;
  const int wid = threadIdx.x >> 6;
  const int t = blockIdx.x * 4 + wid;

  const unsigned s0 = slotinfo[t * 2 + 0];
  const unsigned s1 = slotinfo[t * 2 + 1];
  const int e0 = s0 >> 13, p0 = s0 & 8191;
  const int e1 = s1 >> 13, p1 = s1 & 8191;
  const float w0 = tok_w[e0 * TOKENS + p0];
  const float w1 = tok_w[e1 * TOKENS + p1];
  const size_t r0 = (size_t)(offs[e0] + p0) * DIM;
  const size_t r1 = (size_t)(offs[e1] + p1) * DIM;

  float v[16];
  {
    const float4* i4 = (const float4*)(in_t + (size_t)t * DIM + lane * 16);
    const uint4* y0 = (const uint4*)(y_buf + r0 + lane * 16);
    const uint4* y1 = (const uint4*)(y_buf + r1 + lane * 16);
#pragma unroll
    for (int i = 0; i < 4; ++i) {
      float4 a = i4[i];
      v[i * 4 + 0] = a.x; v[i * 4 + 1] = a.y; v[i * 4 + 2] = a.z; v[i * 4 + 3] = a.w;
    }
#pragma unroll
    for (int i = 0; i < 2; ++i) {
      uint4 u0 = y0[i];
      uint4 u1 = y1[i];
      const unsigned uw0[4] = {u0.x, u0.y, u0.z, u0.w};
      const unsigned uw1[4] = {u1.x, u1.y, u1.z, u1.w};
#pragma unroll
      for (int k = 0; k < 4; ++k) {
        const int base = i * 8 + k * 2;
        v[base + 0] += w0 * bf2f((unsigned short)(uw0[k] & 0xffff)) +
                       w1 * bf2f((unsigned short)(uw1[k] & 0xffff));
        v[base + 1] += w0 * bf2f((unsigned short)(uw0[k] >> 16)) +
                       w1 * bf2f((unsigned short)(uw1[k] >> 16));
      }
    }
  }

  float s = 0.f, s2 = 0.f;
#pragma unroll
  for (int i = 0; i < 16; ++i) { s += v[i]; s2 += v[i] * v[i]; }
#pragma unroll
  for (int sh = 1; sh < 64; sh <<= 1) {
    s += __shfl_xor(s, sh, 64);
    s2 += __shfl_xor(s2, sh, 64);
  }
  const float mu = s * (1.0f / DIM);
  const float var = s2 * (1.0f / DIM) - mu * mu;
  const float rs = rsqrtf(var + 1e-5f);

  float4* w4 = (float4*)(out + (size_t)t * DIM + lane * 16);
#pragma unroll
  for (int i = 0; i < 4; ++i) {
    const int d = lane * 16 + i * 4;
    float4 g = *(const float4*)(gamma + d);
    float4 b = *(const float4*)(beta + d);
    float4 o;
    o.x = (v[i * 4 + 0] - mu) * rs * g.x + b.x;
    o.y = (v[i * 4 + 1] - mu) * rs * g.y + b.y;
    o.z = (v[i * 4 + 2] - mu) * rs * g.z + b.z;
    o.w = (v[i * 4 + 3] - mu) * rs * g.w + b.w;
    w4[i] = o;
  }
}

extern "C" void kernel_launch(void* const* d_in, const int* in_sizes, int n_in,
                              void* d_out, int out_size, void* d_ws, size_t ws_size,
                              hipStream_t stream) {
  const float* hs    = (const float*)d_in[0];
  const float* in_t  = (const float*)d_in[1];
  const float* gw    = (const float*)d_in[2];
  const float* gb    = (const float*)d_in[3];
  const float* w1    = (const float*)d_in[4];
  const float* b1    = (const float*)d_in[5];
  const float* w2    = (const float*)d_in[6];
  const float* b2    = (const float*)d_in[7];
  const float* gamma = (const float*)d_in[8];
  const float* beta  = (const float*)d_in[9];
  float* out = (float*)d_out;
  char* ws = (char*)d_ws;

  // workspace layout (bytes)
  int* counts            = (int*)(ws + 0);                    // 32
  int* offs              = (int*)(ws + 256);                  // 36
  unsigned int* slotinfo = (unsigned int*)(ws + 512);         // 64 KiB
  int* tok_idx           = (int*)(ws + 66048);                // 256 KiB
  float* tok_w           = (float*)(ws + 328192);             // 256 KiB
  unsigned short* hs_bf  = (unsigned short*)(ws + 590336);    // 16 MiB
  unsigned short* w1t    = (unsigned short*)(ws + 17367552);  // 64 MiB [E][F][D]
  unsigned short* w2t    = (unsigned short*)(ws + 84476416);  // 64 MiB [E][D][F]
  unsigned short* h_buf  = (unsigned short*)(ws + 151585280); // 128 MiB [2T][F]
  // y_buf aliases hs_bf + head of w1t: both fully rewritten every call before
  // any reader; y_buf written (MODE1) strictly after their last reader (MODE0).
  unsigned short* y_buf  = (unsigned short*)(ws + 590336);    // 32 MiB [2T][D]

  zero_counts_kernel<<<1, 64, 0, stream>>>(counts);
  router_kernel<<<TOKENS / 4, 256, 0, stream>>>(hs, gw, gb, counts, tok_idx, tok_w,
                                                slotinfo, hs_bf);
  scan_kernel<<<1, 64, 0, stream>>>(counts, offs);
  cast_transpose_kernel<<<dim3(FDIM / 64, DIM / 64, NEXP), 256, 0, stream>>>(w1, w1t, DIM, FDIM);
  cast_transpose_kernel<<<dim3(DIM / 64, FDIM / 64, NEXP), 256, 0, stream>>>(w2, w2t, FDIM, DIM);
  moe_gemm<0, DIM, FDIM><<<dim3(FDIM / 256, TOKENS / 256, NEXP), 512, 0, stream>>>(
      hs_bf, w1t, b1, counts, offs, tok_idx, h_buf);
  moe_gemm<1, FDIM, DIM><<<dim3(DIM / 256, TOKENS / 256, NEXP), 512, 0, stream>>>(
      h_buf, w2t, b2, counts, offs, tok_idx, y_buf);
  ln_combine_kernel<<<TOKENS / 4, 256, 0, stream>>>(y_buf, in_t, offs, slotinfo,
                                                    tok_w, gamma, beta, out);
}

// Round 6
// 785.135 us; speedup vs baseline: 1.2996x; 1.2996x over previous
//
#include <hip/hip_runtime.h>

#define TOKENS 8192
#define DIM 1024
#define NEXP 8
#define FDIM 4096

typedef __bf16 bf16x8 __attribute__((ext_vector_type(8)));
typedef float f32x4 __attribute__((ext_vector_type(4)));

__device__ __forceinline__ unsigned short f2bf(float f) {
  unsigned u = __builtin_bit_cast(unsigned, f);
  u += 0x7fffu + ((u >> 16) & 1u);
  return (unsigned short)(u >> 16);
}

__device__ __forceinline__ float bf2f(unsigned short s) {
  unsigned u = (unsigned)s << 16;
  return __builtin_bit_cast(float, u);
}

__device__ __forceinline__ void gload16(const void* g, void* l) {
  __builtin_amdgcn_global_load_lds(
      (const __attribute__((address_space(1))) unsigned int*)g,
      (__attribute__((address_space(3))) unsigned int*)l, 16, 0, 0);
}

// ---------------- router ----------------
__global__ void zero_counts_kernel(int* counts) {
  if (threadIdx.x < NEXP) counts[threadIdx.x] = 0;
}

// offs + chunked XCD work tables. Chunk = 4 m-tiles x 4 n-tiles of one expert.
// chunks0: MODE0 (16 n-tiles -> 4 n-chunks), chunks1: MODE1 (4 n-tiles -> 1 chunk).
__global__ void scan_kernel(const int* counts, int* offs, int* nchk,
                            int* chunks0, int* chunks1) {
  if (threadIdx.x == 0) {
    int s = 0;
    for (int e = 0; e < NEXP; ++e) { offs[e] = s; s += counts[e]; }
    offs[NEXP] = s;
    int nc0 = 0, nc1 = 0;
    for (int e = 0; e < NEXP; ++e) {
      const int mt = (counts[e] + 255) >> 8;
      for (int mc = 0; mc < mt; mc += 4) {
        for (int n4 = 0; n4 < 16; n4 += 4)
          chunks0[nc0++] = (e << 16) | (mc << 8) | n4;
        chunks1[nc1++] = (e << 16) | (mc << 8);
      }
    }
    nchk[0] = nc0;
    nchk[1] = nc1;
  }
}

__global__ void router_kernel(const float* __restrict__ hs,
                              const float* __restrict__ gw,
                              const float* __restrict__ gb,
                              int* __restrict__ counts,
                              int* __restrict__ tok_idx,
                              float* __restrict__ tok_w,
                              unsigned int* __restrict__ slotinfo,
                              unsigned short* __restrict__ hs_bf) {
  const int lane = threadIdx.x & 63;
  const int wid = threadIdx.x >> 6;
  const int t = blockIdx.x * 4 + wid;
  const float* row = hs + (size_t)t * DIM;

  float x[16];
  const float4* r4 = (const float4*)(row + lane * 16);
#pragma unroll
  for (int i = 0; i < 4; ++i) {
    float4 v = r4[i];
    x[i * 4 + 0] = v.x; x[i * 4 + 1] = v.y; x[i * 4 + 2] = v.z; x[i * 4 + 3] = v.w;
  }

  float acc[8];
#pragma unroll
  for (int e = 0; e < 8; ++e) acc[e] = 0.f;
#pragma unroll
  for (int i = 0; i < 16; ++i) {
    const int d = lane * 16 + i;
    const float4* g4 = (const float4*)(gw + (size_t)d * 8);
    float4 g0 = g4[0], g1 = g4[1];
    const float xv = x[i];
    acc[0] += xv * g0.x; acc[1] += xv * g0.y; acc[2] += xv * g0.z; acc[3] += xv * g0.w;
    acc[4] += xv * g1.x; acc[5] += xv * g1.y; acc[6] += xv * g1.z; acc[7] += xv * g1.w;
  }
#pragma unroll
  for (int sh = 1; sh < 64; sh <<= 1) {
#pragma unroll
    for (int e = 0; e < 8; ++e) acc[e] += __shfl_xor(acc[e], sh, 64);
  }
#pragma unroll
  for (int e = 0; e < 8; ++e) acc[e] += gb[e];

  float mx = acc[0];
#pragma unroll
  for (int e = 1; e < 8; ++e) mx = fmaxf(mx, acc[e]);
  float p[8];
  float sum = 0.f;
#pragma unroll
  for (int e = 0; e < 8; ++e) { p[e] = __expf(acc[e] - mx); sum += p[e]; }
  const float inv = 1.0f / sum;

  int i0 = 0; float b0 = p[0];
#pragma unroll
  for (int e = 1; e < 8; ++e) if (p[e] > b0) { b0 = p[e]; i0 = e; }
  int i1 = -1; float b1v = -1.f;
#pragma unroll
  for (int e = 0; e < 8; ++e) if (e != i0 && p[e] > b1v) { b1v = p[e]; i1 = e; }

  if (lane == 0) {
    int pos0 = atomicAdd(&counts[i0], 1);
    tok_idx[i0 * TOKENS + pos0] = t;
    tok_w[i0 * TOKENS + pos0] = b0 * inv;
    int pos1 = atomicAdd(&counts[i1], 1);
    tok_idx[i1 * TOKENS + pos1] = t;
    tok_w[i1 * TOKENS + pos1] = b1v * inv;
    // pack both slots into one u32: e0:3 | p0:13 | e1:3 | p1:13
    slotinfo[t] = ((unsigned)i0 << 29) | ((unsigned)pos0 << 16) |
                  ((unsigned)i1 << 13) | (unsigned)pos1;
  }

  unsigned short us[16];
#pragma unroll
  for (int i = 0; i < 16; ++i) us[i] = f2bf(x[i]);
  uint4 o0, o1;
  o0.x = (unsigned)us[0] | ((unsigned)us[1] << 16);
  o0.y = (unsigned)us[2] | ((unsigned)us[3] << 16);
  o0.z = (unsigned)us[4] | ((unsigned)us[5] << 16);
  o0.w = (unsigned)us[6] | ((unsigned)us[7] << 16);
  o1.x = (unsigned)us[8] | ((unsigned)us[9] << 16);
  o1.y = (unsigned)us[10] | ((unsigned)us[11] << 16);
  o1.z = (unsigned)us[12] | ((unsigned)us[13] << 16);
  o1.w = (unsigned)us[14] | ((unsigned)us[15] << 16);
  uint4* dst = (uint4*)(hs_bf + (size_t)t * DIM + lane * 16);
  dst[0] = o0;
  dst[1] = o1;
}

// ---------------- transpose + cast weights: src[e][R][C] f32 -> dst[e][C][R] bf16 ----------------
__global__ void cast_transpose_kernel(const float* __restrict__ src,
                                      unsigned short* __restrict__ dst,
                                      int R, int C) {
  __shared__ float tile[64][65];
  const int e = blockIdx.z;
  const int r0 = blockIdx.y * 64;
  const int c0 = blockIdx.x * 64;
  const float* s = src + (size_t)e * R * C;
  unsigned int* d = (unsigned int*)(dst + (size_t)e * R * C);

#pragma unroll
  for (int i = 0; i < 16; ++i) {
    const int idx = threadIdx.x + i * 256;
    const int r = idx >> 6;
    const int c = idx & 63;
    tile[r][c] = s[(size_t)(r0 + r) * C + (c0 + c)];
  }
  __syncthreads();
#pragma unroll
  for (int i = 0; i < 8; ++i) {
    const int idx = threadIdx.x + i * 256;
    const int c = idx >> 5;
    const int r = (idx & 31) * 2;
    unsigned pk = (unsigned)f2bf(tile[r][c]) | ((unsigned)f2bf(tile[r + 1][c]) << 16);
    d[((size_t)(c0 + c) * R + (r0 + r)) >> 1] = pk;
  }
}

// ---------------- grouped GEMM: 256x256 tile, BK=32, 4-slot LDS ring (R4 core) ----------------
// + chunked XCD-aware work decode: block L -> XCD L%8; chunk g = (L>>3>>4)*8 + (L&7);
// within-chunk (L>>3)&15 -> 4m x 4n sub-grid. Co-resident blocks on one XCD share
// 4 A panels + 4 B panels -> staging requests become L2 hits.

#define DO_TILE(sTp, sNp, A0C, B0C, A0N, B0N, STA, STB, WSA, GATESTR, READN, FINAL)   \
  {                                                                                   \
    bf16x8 a1r[4];                                                                    \
    _Pragma("unroll") for (int f_ = 0; f_ < 4; ++f_)                                  \
      a1r[f_] = *(const bf16x8*)((sTp) + aoff[4 + f_]);                               \
    if (STA) {                                                                        \
      gload16(aS0, (WSA));                                                            \
      gload16(aS1, (WSA) + 8192);                                                     \
      aS0 += 64; aS1 += 64;                                                           \
    }                                                                                 \
    __builtin_amdgcn_sched_barrier(0);                                                \
    __builtin_amdgcn_s_setprio(1);                                                    \
    _Pragma("unroll") for (int f_ = 0; f_ < 4; ++f_)                                  \
      _Pragma("unroll") for (int g_ = 0; g_ < 4; ++g_)                                \
        acc[f_][g_] = __builtin_amdgcn_mfma_f32_16x16x32_bf16(                        \
            A0C[f_], B0C[g_], acc[f_][g_], 0, 0, 0);                                  \
    __builtin_amdgcn_s_setprio(0);                                                    \
    __builtin_amdgcn_sched_barrier(0);                                                \
    if (!(FINAL)) {                                                                   \
      asm volatile(GATESTR ::: "memory");                                             \
      __builtin_amdgcn_s_barrier();                                                   \
    }                                                                                 \
    if (READN) {                                                                      \
      _Pragma("unroll") for (int f_ = 0; f_ < 4; ++f_)                                \
        A0N[f_] = *(const bf16x8*)((sNp) + aoff[f_]);                                 \
      _Pragma("unroll") for (int g_ = 0; g_ < 4; ++g_)                                \
        B0N[g_] = *(const bf16x8*)((sNp) + 65536 + boff[g_]);                         \
    }                                                                                 \
    if (STB) {                                                                        \
      gload16(bS0, (WSA) + 65536);                                                    \
      gload16(bS1, (WSA) + 65536 + 8192);                                             \
      bS0 += 64; bS1 += 64;                                                           \
    }                                                                                 \
    __builtin_amdgcn_sched_barrier(0);                                                \
    __builtin_amdgcn_s_setprio(1);                                                    \
    _Pragma("unroll") for (int f_ = 0; f_ < 4; ++f_)                                  \
      _Pragma("unroll") for (int g_ = 0; g_ < 4; ++g_)                                \
        acc[4 + f_][g_] = __builtin_amdgcn_mfma_f32_16x16x32_bf16(                    \
            a1r[f_], B0C[g_], acc[4 + f_][g_], 0, 0, 0);                              \
    __builtin_amdgcn_s_setprio(0);                                                    \
    __builtin_amdgcn_sched_barrier(0);                                                \
  }

template<int MODE, int K, int N>
__global__ __launch_bounds__(512, 2)
void moe_gemm(const unsigned short* __restrict__ Abase,
              const unsigned short* __restrict__ Bbase,
              const float* __restrict__ bias,
              const int* __restrict__ counts,
              const int* __restrict__ offs,
              const int* __restrict__ tok_idx,
              const int* __restrict__ chunktab,
              const int* __restrict__ nchk,
              unsigned short* __restrict__ dst) {
  constexpr int NT = K / 32;  // K-tiles (multiple of 4, >= 8)
  __shared__ __align__(16) unsigned char sm[131072];

  // ---- chunked XCD-aware work decode ----
  const int L = blockIdx.x;
  const int xk = L & 7;          // XCD (dispatch round-robin: id % 8)
  const int tt = L >> 3;
  const int g = (tt >> 4) * 8 + xk;   // chunk id, contiguous range per XCD over time
  if (g >= nchk[MODE]) return;
  const int within = tt & 15;
  const int cd = chunktab[g];
  const int e = cd >> 16;
  const int cnt = counts[e];
  const int m0 = (((cd >> 8) & 255) + (within >> 2)) * 256;
  if (m0 >= cnt) return;
  const int n0 = ((cd & 255) + (within & 3)) * 256;
  const int goff = offs[e];

  const int tid = threadIdx.x;
  const int lane = tid & 63;
  const int wid = tid >> 6;
  const int wr = wid >> 2;   // 0..1 : M band (128 rows)
  const int wcn = wid & 3;   // 0..3 : N band (64 cols)
  const int l15 = lane & 15;
  const int cg = lane >> 4;  // 0..3 : 16B chunk group within 64B row
  const int wdst = wid * 1024;

  // ---- staging source addresses (per thread: rows urow and urow+128) ----
  const int urow = tid >> 2;
  const int uchk = tid & 3;
  const int swz = uchk ^ ((urow >> 1) & 3);  // source pre-swizzle (read-side matched)
  const unsigned char* Bexp = (const unsigned char*)(Bbase + (size_t)e * K * N);

  int gA0 = m0 + urow;       if (gA0 > cnt - 1) gA0 = cnt - 1;
  int gA1 = m0 + urow + 128; if (gA1 > cnt - 1) gA1 = cnt - 1;
  size_t rowA0, rowA1;
  if (MODE == 0) {
    rowA0 = (size_t)tok_idx[e * TOKENS + gA0] * K;
    rowA1 = (size_t)tok_idx[e * TOKENS + gA1] * K;
  } else {
    rowA0 = (size_t)(goff + gA0) * K;
    rowA1 = (size_t)(goff + gA1) * K;
  }
  const unsigned char* aS0 = (const unsigned char*)(Abase + rowA0) + swz * 16;
  const unsigned char* aS1 = (const unsigned char*)(Abase + rowA1) + swz * 16;
  const unsigned char* bS0 = Bexp + (size_t)(n0 + urow) * (K * 2) + swz * 16;
  const unsigned char* bS1 = Bexp + (size_t)(n0 + urow + 128) * (K * 2) + swz * 16;

  // ---- ds_read fragment byte offsets (loop-invariant) ----
  int aoff[8], boff[4];
#pragma unroll
  for (int f = 0; f < 8; ++f) {
    const int r = wr * 128 + f * 16 + l15;
    aoff[f] = r * 64 + ((cg ^ ((r >> 1) & 3)) * 16);
  }
#pragma unroll
  for (int g2 = 0; g2 < 4; ++g2) {
    const int r = wcn * 64 + g2 * 16 + l15;
    boff[g2] = r * 64 + ((cg ^ ((r >> 1) & 3)) * 16);
  }

  f32x4 acc[8][4];
  const f32x4 fz = {0.f, 0.f, 0.f, 0.f};
#pragma unroll
  for (int f = 0; f < 8; ++f)
#pragma unroll
    for (int g2 = 0; g2 < 4; ++g2) acc[f][g2] = fz;

  // ---- prologue: stage K-tiles 0,1,2 (issue order A0,B0,A1,B1,A2,B2) ----
#pragma unroll
  for (int j = 0; j < 3; ++j) {
    gload16(aS0, sm + j * 16384 + wdst);
    gload16(aS1, sm + j * 16384 + wdst + 8192);
    aS0 += 64; aS1 += 64;
    gload16(bS0, sm + 65536 + j * 16384 + wdst);
    gload16(bS1, sm + 65536 + j * 16384 + wdst + 8192);
    bS0 += 64; bS1 += 64;
  }
  asm volatile("s_waitcnt vmcnt(8)" ::: "memory");  // tile 0 (oldest 4 loads) landed
  __builtin_amdgcn_sched_barrier(0);
  __builtin_amdgcn_s_barrier();

  const unsigned char* smc = (const unsigned char*)sm;
  bf16x8 a0A[4], b0A[4], a0B[4], b0B[4];
#pragma unroll
  for (int f = 0; f < 4; ++f) a0A[f] = *(const bf16x8*)(smc + aoff[f]);
#pragma unroll
  for (int g2 = 0; g2 < 4; ++g2) b0A[g2] = *(const bf16x8*)(smc + 65536 + boff[g2]);

  // ---- main loop: 2 K-tiles per iteration, full staging ----
  int t = 0;
#pragma unroll 1
  for (; t + 5 < NT; t += 2) {
    const unsigned char* sT0 = smc + ((t & 3) << 14);
    const unsigned char* sT1 = smc + (((t + 1) & 3) << 14);
    const unsigned char* sT2 = smc + (((t + 2) & 3) << 14);
    unsigned char* w3 = (unsigned char*)sm + (((t + 3) & 3) << 14) + wdst;
    unsigned char* w4 = (unsigned char*)sm + (((t + 4) & 3) << 14) + wdst;
    DO_TILE(sT0, sT1, a0A, b0A, a0B, b0B, 1, 1, w3,
            "s_waitcnt vmcnt(6) lgkmcnt(0)", 1, 0);
    DO_TILE(sT1, sT2, a0B, b0B, a0A, b0A, 1, 1, w4,
            "s_waitcnt vmcnt(6) lgkmcnt(0)", 1, 0);
  }
  // ---- tail: tiles NT-4..NT-1 (t == NT-4 here) ----
  {
    const unsigned char* sT0 = smc + ((t & 3) << 14);
    const unsigned char* sT1 = smc + (((t + 1) & 3) << 14);
    const unsigned char* sT2 = smc + (((t + 2) & 3) << 14);
    const unsigned char* sT3 = smc + (((t + 3) & 3) << 14);
    unsigned char* w3 = (unsigned char*)sm + (((t + 3) & 3) << 14) + wdst;
    DO_TILE(sT0, sT1, a0A, b0A, a0B, b0B, 1, 1, w3,
            "s_waitcnt vmcnt(6) lgkmcnt(0)", 1, 0);       // tile NT-4 (stages NT-1)
    DO_TILE(sT1, sT2, a0B, b0B, a0A, b0A, 0, 0, w3,
            "s_waitcnt vmcnt(4) lgkmcnt(0)", 1, 0);       // tile NT-3
    DO_TILE(sT2, sT3, a0A, b0A, a0B, b0B, 0, 0, w3,
            "s_waitcnt vmcnt(0) lgkmcnt(0)", 1, 0);       // tile NT-2
    DO_TILE(sT3, sT3, a0B, b0B, a0A, b0A, 0, 0, w3,
            "", 0, 1);                                    // tile NT-1 (final)
  }

  // ---- epilogue ----
#pragma unroll
  for (int g2 = 0; g2 < 4; ++g2) {
    const int fcol = n0 + wcn * 64 + g2 * 16 + l15;
    const float bv = bias[e * N + fcol];
#pragma unroll
    for (int f = 0; f < 8; ++f) {
#pragma unroll
      for (int j = 0; j < 4; ++j) {
        const int ml = wr * 128 + f * 16 + cg * 4 + j;
        const int gm = m0 + ml;
        if (gm < cnt) {
          float v = acc[f][g2][j] + bv;
          if (MODE == 0) {
            const float u = 0.7978845608028654f * (v + 0.044715f * v * v * v);
            const float th = 1.0f - 2.0f / (1.0f + __expf(2.0f * u));
            v = 0.5f * v * (1.0f + th);
          }
          dst[(size_t)(goff + gm) * N + fcol] = f2bf(v);
        }
      }
    }
  }
}

// ---------------- fused combine + residual + layernorm ----------------
__global__ void ln_combine_kernel(const unsigned short* __restrict__ y_buf,
                                  const float* __restrict__ in_t,
                                  const int* __restrict__ offs,
                                  const unsigned int* __restrict__ slotinfo,
                                  const float* __restrict__ tok_w,
                                  const float* __restrict__ gamma,
                                  const float* __restrict__ beta,
                                  float* __restrict__ out) {
  const int lane = threadIdx.x & 63;
  const int wid = threadIdx.x >> 6;
  const int t = blockIdx.x * 4 + wid;

  const unsigned s = slotinfo[t];
  const int e0 = s >> 29, p0 = (s >> 16) & 8191;
  const int e1 = (s >> 13) & 7, p1 = s & 8191;
  const float w0 = tok_w[e0 * TOKENS + p0];
  const float w1 = tok_w[e1 * TOKENS + p1];
  const size_t r0 = (size_t)(offs[e0] + p0) * DIM;
  const size_t r1 = (size_t)(offs[e1] + p1) * DIM;

  float v[16];
  {
    const float4* i4 = (const float4*)(in_t + (size_t)t * DIM + lane * 16);
    const uint4* y0 = (const uint4*)(y_buf + r0 + lane * 16);
    const uint4* y1 = (const uint4*)(y_buf + r1 + lane * 16);
#pragma unroll
    for (int i = 0; i < 4; ++i) {
      float4 a = i4[i];
      v[i * 4 + 0] = a.x; v[i * 4 + 1] = a.y; v[i * 4 + 2] = a.z; v[i * 4 + 3] = a.w;
    }
#pragma unroll
    for (int i = 0; i < 2; ++i) {
      uint4 u0 = y0[i];
      uint4 u1 = y1[i];
      const unsigned uw0[4] = {u0.x, u0.y, u0.z, u0.w};
      const unsigned uw1[4] = {u1.x, u1.y, u1.z, u1.w};
#pragma unroll
      for (int k = 0; k < 4; ++k) {
        const int base = i * 8 + k * 2;
        v[base + 0] += w0 * bf2f((unsigned short)(uw0[k] & 0xffff)) +
                       w1 * bf2f((unsigned short)(uw1[k] & 0xffff));
        v[base + 1] += w0 * bf2f((unsigned short)(uw0[k] >> 16)) +
                       w1 * bf2f((unsigned short)(uw1[k] >> 16));
      }
    }
  }

  float sum = 0.f, s2 = 0.f;
#pragma unroll
  for (int i = 0; i < 16; ++i) { sum += v[i]; s2 += v[i] * v[i]; }
#pragma unroll
  for (int sh = 1; sh < 64; sh <<= 1) {
    sum += __shfl_xor(sum, sh, 64);
    s2 += __shfl_xor(s2, sh, 64);
  }
  const float mu = sum * (1.0f / DIM);
  const float var = s2 * (1.0f / DIM) - mu * mu;
  const float rs = rsqrtf(var + 1e-5f);

  float4* w4 = (float4*)(out + (size_t)t * DIM + lane * 16);
#pragma unroll
  for (int i = 0; i < 4; ++i) {
    const int d = lane * 16 + i * 4;
    float4 g = *(const float4*)(gamma + d);
    float4 b = *(const float4*)(beta + d);
    float4 o;
    o.x = (v[i * 4 + 0] - mu) * rs * g.x + b.x;
    o.y = (v[i * 4 + 1] - mu) * rs * g.y + b.y;
    o.z = (v[i * 4 + 2] - mu) * rs * g.z + b.z;
    o.w = (v[i * 4 + 3] - mu) * rs * g.w + b.w;
    w4[i] = o;
  }
}

extern "C" void kernel_launch(void* const* d_in, const int* in_sizes, int n_in,
                              void* d_out, int out_size, void* d_ws, size_t ws_size,
                              hipStream_t stream) {
  const float* hs    = (const float*)d_in[0];
  const float* in_t  = (const float*)d_in[1];
  const float* gw    = (const float*)d_in[2];
  const float* gb    = (const float*)d_in[3];
  const float* w1    = (const float*)d_in[4];
  const float* b1    = (const float*)d_in[5];
  const float* w2    = (const float*)d_in[6];
  const float* b2    = (const float*)d_in[7];
  const float* gamma = (const float*)d_in[8];
  const float* beta  = (const float*)d_in[9];
  float* out = (float*)d_out;
  char* ws = (char*)d_ws;

  // workspace layout (bytes)
  int* counts            = (int*)(ws + 0);                    // 32
  int* offs              = (int*)(ws + 256);                  // 36
  unsigned int* slotinfo = (unsigned int*)(ws + 512);         // 32 KiB (packed)
  int* nchk              = (int*)(ws + 33280);                // 8
  int* chunks0           = (int*)(ws + 33536);                // 512
  int* chunks1           = (int*)(ws + 34048);                // 128
  int* tok_idx           = (int*)(ws + 66048);                // 256 KiB
  float* tok_w           = (float*)(ws + 328192);             // 256 KiB
  unsigned short* hs_bf  = (unsigned short*)(ws + 590336);    // 16 MiB
  unsigned short* w1t    = (unsigned short*)(ws + 17367552);  // 64 MiB [E][F][D]
  unsigned short* w2t    = (unsigned short*)(ws + 84476416);  // 64 MiB [E][D][F]
  unsigned short* h_buf  = (unsigned short*)(ws + 151585280); // 128 MiB [2T][F]
  // y_buf aliases hs_bf + head of w1t: both fully rewritten every call before
  // any reader; y_buf written (MODE1) strictly after their last reader (MODE0).
  unsigned short* y_buf  = (unsigned short*)(ws + 590336);    // 32 MiB [2T][D]

  zero_counts_kernel<<<1, 64, 0, stream>>>(counts);
  router_kernel<<<TOKENS / 4, 256, 0, stream>>>(hs, gw, gb, counts, tok_idx, tok_w,
                                                slotinfo, hs_bf);
  scan_kernel<<<1, 64, 0, stream>>>(counts, offs, nchk, chunks0, chunks1);
  cast_transpose_kernel<<<dim3(FDIM / 64, DIM / 64, NEXP), 256, 0, stream>>>(w1, w1t, DIM, FDIM);
  cast_transpose_kernel<<<dim3(DIM / 64, FDIM / 64, NEXP), 256, 0, stream>>>(w2, w2t, FDIM, DIM);
  // grids: worst-case chunk counts (MODE0 <= 96 chunks -> 12 slots; MODE1 <= 24 -> 3)
  moe_gemm<0, DIM, FDIM><<<1536, 512, 0, stream>>>(
      hs_bf, w1t, b1, counts, offs, tok_idx, chunks0, nchk, h_buf);
  moe_gemm<1, FDIM, DIM><<<384, 512, 0, stream>>>(
      h_buf, w2t, b2, counts, offs, tok_idx, chunks1, nchk, y_buf);
  ln_combine_kernel<<<TOKENS / 4, 256, 0, stream>>>(y_buf, in_t, offs, slotinfo,
                                                    tok_w, gamma, beta, out);
}